// Round 4
// baseline (447.493 us; speedup 1.0000x reference)
//
#include <hip/hip_runtime.h>
#include <stdint.h>

#define FP8_MAX 448.0f
#define TOKENS  8192
#define IDIM    4096
#define ODIM    4096

typedef float f32x4 __attribute__((ext_vector_type(4)));
typedef int   i32x4 __attribute__((ext_vector_type(4)));
typedef int   i32x8 __attribute__((ext_vector_type(8)));

__device__ __forceinline__ void async_copy16(const uint8_t* g, uint8_t* l) {
  __builtin_amdgcn_global_load_lds((const __attribute__((address_space(1))) void*)g,
                                   (__attribute__((address_space(3))) void*)l,
                                   16, 0, 0);
}

__device__ __forceinline__ i32x8 ldfrag(const uint8_t* p, int o0, int o1) {
  i32x4 lo = *(const i32x4*)(p + o0);
  i32x4 hi = *(const i32x4*)(p + o1);
  return __builtin_shufflevector(lo, hi, 0, 1, 2, 3, 4, 5, 6, 7);
}

// ---------------- fused prep, wave-per-row (unchanged from round 3) ----------------
__global__ __launch_bounds__(256) void prep_kernel(
    const float* __restrict__ x, const float* __restrict__ w,
    uint8_t* __restrict__ xq, uint8_t* __restrict__ wq, float* __restrict__ xsc) {
  const int lane = threadIdx.x & 63;
  const int wid  = threadIdx.x >> 6;

  if (blockIdx.x < 2048) {
    const int row = blockIdx.x * 4 + wid;
    const f32x4* xr = (const f32x4*)(x + (size_t)row * IDIM);

    f32x4 v[16];
    float amax = 0.0f;
    #pragma unroll
    for (int k = 0; k < 16; k++) {
      v[k] = xr[lane + k * 64];
      amax = fmaxf(amax, fmaxf(fmaxf(fabsf(v[k].x), fabsf(v[k].y)),
                               fmaxf(fabsf(v[k].z), fabsf(v[k].w))));
    }
    #pragma unroll
    for (int off = 32; off > 0; off >>= 1)
      amax = fmaxf(amax, __shfl_xor(amax, off, 64));
    amax = fmaxf(amax, 1e-12f);
    const float scale = amax / FP8_MAX;     // matches ref: amax/448 in f32
    if (lane == 0) xsc[row] = scale;

    uint32_t* out = (uint32_t*)(xq + (size_t)row * IDIM);
    #pragma unroll
    for (int k = 0; k < 16; k++) {
      // exact f32 divide to match reference rounding, then RNE fp8 cast
      float a = v[k].x / scale, b = v[k].y / scale;
      float c = v[k].z / scale, d = v[k].w / scale;
      int p = __builtin_amdgcn_cvt_pk_fp8_f32(a, b, 0, false);
      p = __builtin_amdgcn_cvt_pk_fp8_f32(c, d, p, true);
      out[lane + k * 64] = (uint32_t)p;
    }
  } else {
    const int row = (blockIdx.x - 2048) * 4 + wid;
    const f32x4* wp = (const f32x4*)(w + (size_t)row * IDIM);
    uint32_t* out = (uint32_t*)(wq + (size_t)row * IDIM);
    #pragma unroll
    for (int k = 0; k < 16; k++) {
      f32x4 t = wp[lane + k * 64];
      int p = __builtin_amdgcn_cvt_pk_fp8_f32(t.x, t.y, 0, false);
      p = __builtin_amdgcn_cvt_pk_fp8_f32(t.z, t.w, p, true);
      out[lane + k * 64] = (uint32_t)p;
    }
  }
}

// ---------------- fp8 block-scaled GEMM: 256x256 tile, counted-vmcnt raw-barrier pipeline ----------------
// y[t][o] = x_scale[t] * sum_kb wsi[o/128][kb] * sum_{k in kb} xq[t][k]*wq[o][k]
// 512 thr = 8 waves (2M x 4N), per-wave 128x64 output (8x4 16x16 frags), BK=128.
// Per K-tile: {issue 8 gload_lds for tile kb+1 | s_waitcnt vmcnt(8): wait ONLY tile kb's
// loads (kb+1's stay in flight under the MFMAs) | s_barrier | 32 MFMA w/ compiler-scheduled
// ds_reads | s_barrier}. No __syncthreads -> no vmcnt(0) drain (the round-0/3 ceiling).
// No sched_barrier(0) (round-2 spill cause); only empty-asm compiler fences at barriers.
// 256^2 tile halves L2-fill traffic vs 128^2 (2.1GB -> 1.05GB, 30us floor vs 59us MFMA floor).
__global__ __launch_bounds__(512, 2) void gemm_fp8_kernel(
    const uint8_t* __restrict__ xq, const uint8_t* __restrict__ wq,
    const float* __restrict__ xsc, const float* __restrict__ wsi,
    float* __restrict__ y) {
  __shared__ __align__(16) uint8_t As0[32768];
  __shared__ __align__(16) uint8_t Bs0[32768];
  __shared__ __align__(16) uint8_t As1[32768];
  __shared__ __align__(16) uint8_t Bs1[32768];

  const int tid  = threadIdx.x;
  const int bo   = blockIdx.x & 15;   // 16 o-tiles (fastest: neighbors share A-panel)
  const int bt   = blockIdx.x >> 4;   // 32 t-tiles
  const int t0   = bt << 8;
  const int o0   = bo << 8;
  const int lane = tid & 63;
  const int wv   = tid >> 6;
  const int wr   = (wv >> 2) << 7;    // 0 / 128 : wave token offset
  const int wc   = (wv & 3) << 6;     // 0/64/128/192 : wave output offset
  const int ln   = lane & 15;
  const int quad = lane >> 4;

  // Staging: 8 x 16B/thread per K-tile (4 u-groups x A,B). Row = u*64 + (tid>>3);
  // global src chunk = (tid&7) ^ (row&7) (XOR swizzle in src addr; LDS dst linear).
  const int rb  = tid >> 3;
  const int cs  = ((tid & 7) ^ (rb & 7)) << 4;
  const int dst = tid << 4;

  // MFMA A/B operand (16x16x128): row = lane&15, k bytes = quad*32..+32
  // -> 16B chunks c0, c0+1 of row, XOR-unswizzled.
  const int c0   = quad << 1;
  const int sw   = ln & 7;
  const int sw0  = ((c0    ) ^ sw) << 4;
  const int sw1  = ((c0 + 1) ^ sw) << 4;
  const int ab   = (wr + ln) * 128;   // A byte base (row stride 128B)
  const int bb   = (wc + ln) * 128;   // B byte base

  f32x4 outer[8][4];
  #pragma unroll
  for (int i = 0; i < 8; i++)
    #pragma unroll
    for (int j = 0; j < 4; j++)
      outer[i][j] = (f32x4)(0.0f);

  // wave's 64-col slice sits in one 128-col scale block
  const float* wsrow = wsi + (bo * 2 + (wc >> 7)) * 32;
  const int ident = 0x7f7f7f7f;       // e8m0 identity scale
  const f32x4 zero4 = (f32x4)(0.0f);

  auto stage = [&](uint8_t* Aw, uint8_t* Bw, int k0) {
    #pragma unroll
    for (int u = 0; u < 4; u++)
      async_copy16(xq + ((size_t)(t0 + u * 64 + rb) << 12) + (k0 + cs),
                   Aw + u * 8192 + dst);
    #pragma unroll
    for (int u = 0; u < 4; u++)
      async_copy16(wq + ((size_t)(o0 + u * 64 + rb) << 12) + (k0 + cs),
                   Bw + u * 8192 + dst);
  };

  // compute one K-tile: hold b[4] (32 VGPR), stream a in two halves (32 VGPR)
  auto compute = [&](const uint8_t* Ab, const uint8_t* Bb, float s) {
    i32x8 a[4], b[4];
    #pragma unroll
    for (int j = 0; j < 4; j++)
      b[j] = ldfrag(Bb + bb + j * 2048, sw0, sw1);
    #pragma unroll
    for (int i = 0; i < 4; i++)
      a[i] = ldfrag(Ab + ab + i * 2048, sw0, sw1);
    __builtin_amdgcn_s_setprio(1);
    #pragma unroll
    for (int i = 0; i < 4; i++)
      #pragma unroll
      for (int j = 0; j < 4; j++) {
        f32x4 t = __builtin_amdgcn_mfma_scale_f32_16x16x128_f8f6f4(
            a[i], b[j], zero4, 0, 0, 0, ident, 0, ident);
        outer[i][j] += s * t;
      }
    __builtin_amdgcn_s_setprio(0);
    #pragma unroll
    for (int i = 0; i < 4; i++)
      a[i] = ldfrag(Ab + ab + 8192 + i * 2048, sw0, sw1);
    __builtin_amdgcn_s_setprio(1);
    #pragma unroll
    for (int i = 0; i < 4; i++)
      #pragma unroll
      for (int j = 0; j < 4; j++) {
        f32x4 t = __builtin_amdgcn_mfma_scale_f32_16x16x128_f8f6f4(
            a[i], b[j], zero4, 0, 0, 0, ident, 0, ident);
        outer[i + 4][j] += s * t;
      }
    __builtin_amdgcn_s_setprio(0);
  };

  // prologue: stage tile 0 (8 loads in flight)
  stage(As0, Bs0, 0);

  #pragma unroll 1
  for (int kb = 0; kb < 32; kb += 2) {
    // ---- tile kb (reads As0/Bs0, stages kb+1 into As1/Bs1) ----
    stage(As1, Bs1, ((kb + 1) & 31) << 7);
    asm volatile("s_waitcnt vmcnt(8)" ::: "memory");  // tile kb's loads done; kb+1's in flight
    __builtin_amdgcn_s_barrier();                     // all waves: buffer 0 valid
    asm volatile("" ::: "memory");                    // no ds_read hoist above barrier
    compute(As0, Bs0, wsrow[kb]);
    asm volatile("" ::: "memory");                    // no stage-issue sink above barrier
    __builtin_amdgcn_s_barrier();                     // all waves done reading buffer 0
    asm volatile("" ::: "memory");

    // ---- tile kb+1 (reads As1/Bs1, stages kb+2 into As0/Bs0) ----
    stage(As0, Bs0, ((kb + 2) & 31) << 7);            // kb=30: redundant tile-0 load, never read
    asm volatile("s_waitcnt vmcnt(8)" ::: "memory");
    __builtin_amdgcn_s_barrier();
    asm volatile("" ::: "memory");
    compute(As1, Bs1, wsrow[kb + 1]);
    asm volatile("" ::: "memory");
    __builtin_amdgcn_s_barrier();
    asm volatile("" ::: "memory");
  }

  // epilogue: C/D frag (row = quad*4+reg -> token, col = ln -> output), * x_scale[t]
  #pragma unroll
  for (int i = 0; i < 8; i++) {
    #pragma unroll
    for (int r = 0; r < 4; r++) {
      const int t = t0 + wr + i * 16 + quad * 4 + r;
      const float sc = xsc[t];
      float* yp = y + ((size_t)t << 12) + o0 + wc + ln;
      #pragma unroll
      for (int j = 0; j < 4; j++)
        yp[j * 16] = outer[i][j][r] * sc;
    }
  }
}

extern "C" void kernel_launch(void* const* d_in, const int* in_sizes, int n_in,
                              void* d_out, int out_size, void* d_ws, size_t ws_size,
                              hipStream_t stream) {
  const float* x   = (const float*)d_in[0];   // [8192,4096] f32
  const float* w   = (const float*)d_in[1];   // [4096,4096] f32 (fp8-valued)
  const float* wsi = (const float*)d_in[2];   // [32,32] f32
  float* y = (float*)d_out;                   // [8192,4096] f32

  // workspace layout: 33.55MB xq + 16.78MB wq + 32KB xsc
  uint8_t* xq = (uint8_t*)d_ws;
  uint8_t* wq = xq + (size_t)TOKENS * IDIM;
  float*  xsc = (float*)(wq + (size_t)ODIM * IDIM);

  prep_kernel<<<3072, 256, 0, stream>>>(x, w, xq, wq, xsc);
  gemm_fp8_kernel<<<(TOKENS / 256) * (ODIM / 256), 512, 0, stream>>>(xq, wq, xsc, wsi, y);
}